// Round 5
// baseline (754.042 us; speedup 1.0000x reference)
//
#include <hip/hip_runtime.h>

#define NN 50000
#define EE 800000

typedef __bf16 bf16x8 __attribute__((ext_vector_type(8)));
typedef float  f32x4  __attribute__((ext_vector_type(4)));

__device__ __forceinline__ float bf2f(ushort u) {
    union { unsigned int i; float f; } v; v.i = ((unsigned int)u) << 16; return v.f;
}
__device__ __forceinline__ ushort f2bf(float f) {
    union { float f; unsigned int i; } v; v.f = f;
    unsigned int u = v.i;
    return (ushort)((u + 0x7FFFu + ((u >> 16) & 1u)) >> 16);
}
__device__ __forceinline__ float silu(float x) { return x / (1.0f + __expf(-x)); }

// ---------------------------------------------------------------------------
// Dtype detection (0 = bf16 inputs, 1 = f32 inputs).
// ---------------------------------------------------------------------------
__global__ void detect_kernel(const ushort* __restrict__ xzu, int* __restrict__ flag) {
    __shared__ int cnt;
    if (threadIdx.x == 0) cnt = 0;
    __syncthreads();
    float v = bf2f(xzu[2 * threadIdx.x]);
    bool sane = (v == v) && (fabsf(v) <= 4.0f);
    if (sane) atomicAdd(&cnt, 1);
    __syncthreads();
    if (threadIdx.x == 0) *flag = (cnt >= 192) ? 0 : 1;
}

__global__ void ingest_h(const void* __restrict__ hsrc, const int* __restrict__ flag,
                         ushort* __restrict__ hb) {
    const bool isf = (*flag != 0);
    int i = blockIdx.x * 256 + threadIdx.x;
    if (i >= NN * 128) return;
    hb[i] = isf ? f2bf(((const float*)hsrc)[i]) : ((const ushort*)hsrc)[i];
}

__global__ void ingest_xz(const void* __restrict__ src, const int* __restrict__ flag,
                          float* __restrict__ xzf) {
    const bool isf = (*flag != 0);
    int i = blockIdx.x * 256 + threadIdx.x;
    if (i >= NN * 3) return;
    xzf[i] = isf ? ((const float*)src)[i] : bf2f(((const ushort*)src)[i]);
}

// f32 block: [0:128)=be1 [128:256)=be2 [256:384)=bn1 [384:512)=bn2 [512:640)=We1[256][:]
__global__ void ingest_misc(const void* be1, const void* be2, const void* bn1, const void* bn2,
                            const void* We1, const int* __restrict__ flag,
                            float* __restrict__ fb) {
    const bool isf = (*flag != 0);
    for (int j = threadIdx.x; j < 640; j += 256) {
        int which = j >> 7, k = j & 127;
        const void* src = (which == 0) ? be1 : (which == 1) ? be2 :
                          (which == 2) ? bn1 : (which == 3) ? bn2 : We1;
        size_t idx = (which == 4) ? ((size_t)256 * 128 + k) : (size_t)k;
        fb[j] = isf ? ((const float*)src)[idx] : bf2f(((const ushort*)src)[idx]);
    }
}

// ---------------------------------------------------------------------------
// Weight swizzle into MFMA B-fragment order, dual-dtype read.
// ---------------------------------------------------------------------------
__global__ void swizzle_kernel(const void* We1, const void* We2,
                               const void* Wn1, const void* Wn2,
                               const int* __restrict__ flag,
                               ushort* __restrict__ We1s, ushort* __restrict__ We2s,
                               ushort* __restrict__ Wn1s, ushort* __restrict__ Wn2s) {
    const bool isf = (*flag != 0);
    int c = blockIdx.x * blockDim.x + threadIdx.x;
    const void* src; ushort* dst; int cl;
    if      (c <  4096) { src = We1; dst = We1s; cl = c;         }
    else if (c <  6144) { src = We2; dst = We2s; cl = c - 4096;  }
    else if (c < 10240) { src = Wn1; dst = Wn1s; cl = c - 6144;  }
    else if (c < 12288) { src = Wn2; dst = Wn2s; cl = c - 10240; }
    else return;
    int l = cl & 63, nt = (cl >> 6) & 7, kc = cl >> 9;
    int kbase = kc * 32 + (l >> 4) * 8;
    int n = nt * 16 + (l & 15);
    ushort tmp[8];
#pragma unroll
    for (int j = 0; j < 8; ++j) {
        size_t idx = (size_t)(kbase + j) * 128 + n;
        tmp[j] = isf ? f2bf(((const float*)src)[idx]) : ((const ushort*)src)[idx];
    }
#pragma unroll
    for (int j = 0; j < 8; ++j) dst[(size_t)cl * 8 + j] = tmp[j];
}

// ---------------------------------------------------------------------------
// Counting sort of edges by destination row.
// ---------------------------------------------------------------------------
__global__ void hist_kernel(const int* __restrict__ erow, int* __restrict__ cntI) {
    int e = blockIdx.x * 256 + threadIdx.x;
    if (e < EE) atomicAdd(&cntI[erow[e]], 1);
}

__global__ void scan_kernel(const int* __restrict__ cntI, int* __restrict__ basep) {
    __shared__ int s[1024];
    __shared__ int carry;
    if (threadIdx.x == 0) carry = 0;
    __syncthreads();
    for (int c0 = 0; c0 < NN; c0 += 1024) {
        int i = c0 + threadIdx.x;
        int v = (i < NN) ? cntI[i] : 0;
        s[threadIdx.x] = v;
        __syncthreads();
        for (int d = 1; d < 1024; d <<= 1) {
            int t = (threadIdx.x >= (unsigned)d) ? s[threadIdx.x - d] : 0;
            __syncthreads();
            s[threadIdx.x] += t;
            __syncthreads();
        }
        if (i < NN) basep[i] = carry + s[threadIdx.x] - v;   // exclusive
        __syncthreads();
        if (threadIdx.x == 1023) carry += s[1023];
        __syncthreads();
    }
}

__global__ void scatter_kernel(const int* __restrict__ erow, const int* __restrict__ ecol,
                               const int* __restrict__ basep, int* __restrict__ ctr,
                               int* __restrict__ srow, int* __restrict__ scol) {
    int e = blockIdx.x * 256 + threadIdx.x;
    if (e < EE) {
        int r = erow[e];
        int p = basep[r] + atomicAdd(&ctr[r], 1);
        srow[p] = r;
        scol[p] = ecol[e];
    }
}

// ---------------------------------------------------------------------------
// Edge kernel (sorted edges): per 64-edge tile
//   A = [h[row] | h[col]] K=256, dist as rank-1 epilogue.
//   m1 = silu(...) -> sM;  m2 = silu(m1@We2+be2) -> sP (LDS, f32, XOR-swizzled)
//   -> wave-uniform segmented reduction over sorted rows -> few atomics.
// ---------------------------------------------------------------------------
__global__ __launch_bounds__(256, 3) void edge_kernel(
    const ushort* __restrict__ hb, const float* __restrict__ xzf,
    const int* __restrict__ srow, const int* __restrict__ scol,
    const ushort* __restrict__ We1s, const ushort* __restrict__ We2s,
    const float* __restrict__ fb, float* __restrict__ agg) {
    __shared__ __align__(16) ushort sA[16384];   // 32KB: A-frags, then reused as f32 sP[64][128]
    __shared__ __align__(16) ushort sM[8192];    // 16KB: m1 frags
    __shared__ float sDist[64];
    __shared__ int   sRowIdx[64];

    const int tid = threadIdx.x;
    const int lane = tid & 63, w = tid >> 6;
    const int col = lane & 15, quad = lane >> 4;
    const int nt0 = w * 2;
    float* sP = (float*)sA;

    // preload all We1 B-fragments for this wave's 32-col slice into registers
    bf16x8 B1[16];
#pragma unroll
    for (int kc = 0; kc < 8; ++kc) {
        B1[kc * 2]     = *(const bf16x8*)(We1s + ((kc * 8 + nt0)     * 64 + lane) * 8);
        B1[kc * 2 + 1] = *(const bf16x8*)(We1s + ((kc * 8 + nt0 + 1) * 64 + lane) * 8);
    }

    for (int tile = blockIdx.x; tile < EE / 64; tile += gridDim.x) {
        __syncthreads();
        const int e0 = tile * 64;
        if (tid < 64) {
            int e = e0 + tid;
            int r = srow[e], c = scol[e];
            sRowIdx[tid] = r;
            float x1 = xzf[3 * r], y1 = xzf[3 * r + 1], z1 = xzf[3 * r + 2];
            float x2 = xzf[3 * c], y2 = xzf[3 * c + 1], z2 = xzf[3 * c + 2];
            float dx = x1 - x2, dy = y1 - y2, dzv = z1 - z2;
            float u = (dx * dx + dy * dy + dzv * dzv) / (2.0f * z1 * z2);
            u = fminf(fmaxf(u, 0.0f), 1.0e6f);
            sDist[tid] = __logf(1.0f + u + sqrtf(u * (u + 2.0f)));
        }
#pragma unroll
        for (int i = 0; i < 8; ++i) {
            int cidx = tid + i * 256;
            int m = cidx & 63, kb = cidx >> 6;
            int e = e0 + m;
            int src_node = (kb < 16) ? srow[e] : scol[e];
            int k0 = (kb & 15) * 8;
            uint4 v = *(const uint4*)(hb + (size_t)src_node * 128 + k0);
            int g = m >> 4, ml = m & 15, kc = kb >> 2, q = kb & 3;
            *(uint4*)(sA + ((g * 8 + kc) * 64 + q * 16 + ml) * 8) = v;
        }
        __syncthreads();

        // ---- GEMM1 (B from registers) ----
        f32x4 acc[4][2] = {};
#pragma unroll
        for (int kc = 0; kc < 8; ++kc) {
#pragma unroll
            for (int g = 0; g < 4; ++g) {
                bf16x8 a = *(const bf16x8*)(sA + ((g * 8 + kc) * 64 + lane) * 8);
                acc[g][0] = __builtin_amdgcn_mfma_f32_16x16x32_bf16(a, B1[kc * 2],     acc[g][0], 0, 0, 0);
                acc[g][1] = __builtin_amdgcn_mfma_f32_16x16x32_bf16(a, B1[kc * 2 + 1], acc[g][1], 0, 0, 0);
            }
        }
#pragma unroll
        for (int g = 0; g < 4; ++g) {
#pragma unroll
            for (int t = 0; t < 2; ++t) {
                int n = w * 32 + t * 16 + col;
                float wl = fb[512 + n];
                float bb = fb[n];
                int base = ((g * 4 + w) * 64 + (t * 2 + (col >> 3)) * 16) * 8 + (col & 7);
#pragma unroll
                for (int r = 0; r < 4; ++r) {
                    int mrow = quad * 4 + r;
                    float x = acc[g][t][r] + sDist[g * 16 + mrow] * wl + bb;
                    sM[base + mrow * 8] = f2bf(silu(x));
                }
            }
        }
        __syncthreads();   // sM ready; also: all sA reads (GEMM1) done -> sP reuse safe

        // ---- GEMM2 ----
        f32x4 acc2[4][2] = {};
#pragma unroll
        for (int kc = 0; kc < 4; ++kc) {
            bf16x8 b0 = *(const bf16x8*)(We2s + ((kc * 8 + nt0)     * 64 + lane) * 8);
            bf16x8 b1 = *(const bf16x8*)(We2s + ((kc * 8 + nt0 + 1) * 64 + lane) * 8);
#pragma unroll
            for (int g = 0; g < 4; ++g) {
                bf16x8 a = *(const bf16x8*)(sM + ((g * 4 + kc) * 64 + lane) * 8);
                acc2[g][0] = __builtin_amdgcn_mfma_f32_16x16x32_bf16(a, b0, acc2[g][0], 0, 0, 0);
                acc2[g][1] = __builtin_amdgcn_mfma_f32_16x16x32_bf16(a, b1, acc2[g][1], 0, 0, 0);
            }
        }
        // epilogue: silu -> sP[m][n] f32 (XOR-swizzled banks)
#pragma unroll
        for (int g = 0; g < 4; ++g) {
#pragma unroll
            for (int t = 0; t < 2; ++t) {
                int n = w * 32 + t * 16 + col;
                float bb = fb[128 + n];
#pragma unroll
                for (int r = 0; r < 4; ++r) {
                    int m = g * 16 + quad * 4 + r;
                    sP[m * 128 + (n ^ (m & 28))] = silu(acc2[g][t][r] + bb);
                }
            }
        }
        __syncthreads();

        // ---- segmented reduction over sorted rows ----
        {
            int n = tid & 127;          // column
            int m0 = (tid >> 7) * 32;   // half: wave-uniform
            int cur = sRowIdx[m0];
            float run = 0.0f;
#pragma unroll 8
            for (int i = 0; i < 32; ++i) {
                int m = m0 + i;
                int rw = sRowIdx[m];            // wave-uniform broadcast
                float v = sP[m * 128 + (n ^ (m & 28))];
                if (rw != cur) {                // wave-uniform branch
                    unsafeAtomicAdd(&agg[(size_t)cur * 128 + n], run);
                    cur = rw; run = v;
                } else {
                    run += v;
                }
            }
            unsafeAtomicAdd(&agg[(size_t)cur * 128 + n], run);
        }
    }
}

// ---------------------------------------------------------------------------
// Node kernel: z = [h | agg/max(cnt,1)]; out = h + silu(z@Wn1+bn1)@Wn2+bn2
// ---------------------------------------------------------------------------
__global__ __launch_bounds__(256, 3) void node_kernel(
    const ushort* __restrict__ hb, const void* __restrict__ hraw,
    const float* __restrict__ agg, const int* __restrict__ cntI,
    const ushort* __restrict__ Wn1s, const ushort* __restrict__ Wn2s,
    const float* __restrict__ fb, const int* __restrict__ flag,
    void* __restrict__ outv) {
    __shared__ __align__(16) ushort sA[16384];
    __shared__ __align__(16) ushort sM[8192];
    const int tid = threadIdx.x;
    const int lane = tid & 63, w = tid >> 6;
    const int col = lane & 15, quad = lane >> 4;
    const int nt0 = w * 2;
    const int ntiles = (NN + 63) / 64;
    const bool isf = (*flag != 0);
    float* outf = (float*)outv;
    ushort* outu = (ushort*)outv;

    for (int tile = blockIdx.x; tile < ntiles; tile += gridDim.x) {
        __syncthreads();
        const int n0 = tile * 64;
#pragma unroll
        for (int i = 0; i < 8; ++i) {
            int cidx = tid + i * 256;
            int m = cidx & 63, kb = cidx >> 6;
            int node = n0 + m;
            int g = m >> 4, ml = m & 15, kc = kb >> 2, q = kb & 3;
            uint4 v;
            if (node < NN) {
                if (kb < 16) {
                    v = *(const uint4*)(hb + (size_t)node * 128 + kb * 8);
                } else {
                    int kk = (kb - 16) * 8;
                    const float* ap = agg + (size_t)node * 128 + kk;
                    float invc = 1.0f / fmaxf((float)cntI[node], 1.0f);
                    float4 f0 = *(const float4*)ap;
                    float4 f1 = *(const float4*)(ap + 4);
                    v.x = (unsigned int)f2bf(f0.x * invc) | ((unsigned int)f2bf(f0.y * invc) << 16);
                    v.y = (unsigned int)f2bf(f0.z * invc) | ((unsigned int)f2bf(f0.w * invc) << 16);
                    v.z = (unsigned int)f2bf(f1.x * invc) | ((unsigned int)f2bf(f1.y * invc) << 16);
                    v.w = (unsigned int)f2bf(f1.z * invc) | ((unsigned int)f2bf(f1.w * invc) << 16);
                }
            } else {
                v = make_uint4(0, 0, 0, 0);
            }
            *(uint4*)(sA + ((g * 8 + kc) * 64 + q * 16 + ml) * 8) = v;
        }
        __syncthreads();

        f32x4 acc[4][2] = {};
#pragma unroll 2
        for (int kc = 0; kc < 8; ++kc) {
            bf16x8 b0 = *(const bf16x8*)(Wn1s + ((kc * 8 + nt0)     * 64 + lane) * 8);
            bf16x8 b1 = *(const bf16x8*)(Wn1s + ((kc * 8 + nt0 + 1) * 64 + lane) * 8);
#pragma unroll
            for (int g = 0; g < 4; ++g) {
                bf16x8 a = *(const bf16x8*)(sA + ((g * 8 + kc) * 64 + lane) * 8);
                acc[g][0] = __builtin_amdgcn_mfma_f32_16x16x32_bf16(a, b0, acc[g][0], 0, 0, 0);
                acc[g][1] = __builtin_amdgcn_mfma_f32_16x16x32_bf16(a, b1, acc[g][1], 0, 0, 0);
            }
        }
#pragma unroll
        for (int g = 0; g < 4; ++g) {
#pragma unroll
            for (int t = 0; t < 2; ++t) {
                int n = w * 32 + t * 16 + col;
                float bb = fb[256 + n];
                int base = ((g * 4 + w) * 64 + (t * 2 + (col >> 3)) * 16) * 8 + (col & 7);
#pragma unroll
                for (int r = 0; r < 4; ++r) {
                    int mrow = quad * 4 + r;
                    sM[base + mrow * 8] = f2bf(silu(acc[g][t][r] + bb));
                }
            }
        }
        __syncthreads();

        f32x4 acc2[4][2] = {};
#pragma unroll
        for (int kc = 0; kc < 4; ++kc) {
            bf16x8 b0 = *(const bf16x8*)(Wn2s + ((kc * 8 + nt0)     * 64 + lane) * 8);
            bf16x8 b1 = *(const bf16x8*)(Wn2s + ((kc * 8 + nt0 + 1) * 64 + lane) * 8);
#pragma unroll
            for (int g = 0; g < 4; ++g) {
                bf16x8 a = *(const bf16x8*)(sM + ((g * 4 + kc) * 64 + lane) * 8);
                acc2[g][0] = __builtin_amdgcn_mfma_f32_16x16x32_bf16(a, b0, acc2[g][0], 0, 0, 0);
                acc2[g][1] = __builtin_amdgcn_mfma_f32_16x16x32_bf16(a, b1, acc2[g][1], 0, 0, 0);
            }
        }
#pragma unroll
        for (int g = 0; g < 4; ++g) {
#pragma unroll
            for (int t = 0; t < 2; ++t) {
                int n = w * 32 + t * 16 + col;
                float bb = fb[384 + n];
#pragma unroll
                for (int r = 0; r < 4; ++r) {
                    int ml2 = g * 16 + quad * 4 + r;
                    int node = n0 + ml2;
                    if (node < NN) {
                        size_t oi = (size_t)node * 128 + n;
                        float hres = isf ? ((const float*)hraw)[oi] : bf2f(((const ushort*)hraw)[oi]);
                        float x = acc2[g][t][r] + bb + hres;
                        if (isf) outf[oi] = x; else outu[oi] = f2bf(x);
                    }
                }
            }
        }
    }
}

extern "C" void kernel_launch(void* const* d_in, const int* in_sizes, int n_in,
                              void* d_out, int out_size, void* d_ws, size_t ws_size,
                              hipStream_t stream) {
    const void* xz  = d_in[0];
    const void* h   = d_in[1];
    const void* We1 = d_in[2];
    const void* be1 = d_in[3];
    const void* We2 = d_in[4];
    const void* be2 = d_in[5];
    const void* Wn1 = d_in[6];
    const void* bn1 = d_in[7];
    const void* Wn2 = d_in[8];
    const void* bn2 = d_in[9];
    const int*  ei  = (const int*)d_in[10];
    const int* erow = ei;
    const int* ecol = ei + EE;

    char* base = (char*)d_ws;
    size_t cur = 0;
    auto alloc = [&](size_t bytes) { size_t o = cur; cur = (cur + bytes + 255) & ~(size_t)255; return o; };
    int*    flag = (int*)   (base + alloc(16));
    float*  agg  = (float*) (base + alloc((size_t)NN * 128 * 4));
    int*    cntI = (int*)   (base + alloc((size_t)NN * 4));
    int*    ctr  = (int*)   (base + alloc((size_t)NN * 4));
    int*    basep= (int*)   (base + alloc((size_t)(NN + 1) * 4));
    int*    srow = (int*)   (base + alloc((size_t)EE * 4));
    int*    scol = (int*)   (base + alloc((size_t)EE * 4));
    ushort* hb   = (ushort*)(base + alloc((size_t)NN * 128 * 2));
    float*  xzf  = (float*) (base + alloc((size_t)NN * 3 * 4));
    ushort* We1s = (ushort*)(base + alloc(32768 * 2));
    ushort* We2s = (ushort*)(base + alloc(16384 * 2));
    ushort* Wn1s = (ushort*)(base + alloc(32768 * 2));
    ushort* Wn2s = (ushort*)(base + alloc(16384 * 2));
    float*  fb   = (float*) (base + alloc(640 * 4));

    (void)hipMemsetAsync(agg, 0, (size_t)NN * 128 * sizeof(float), stream);
    (void)hipMemsetAsync(cntI, 0, (size_t)NN * sizeof(int), stream);
    (void)hipMemsetAsync(ctr, 0, (size_t)NN * sizeof(int), stream);

    detect_kernel<<<1, 256, 0, stream>>>((const ushort*)xz, flag);
    ingest_h<<<(NN * 128 + 255) / 256, 256, 0, stream>>>(h, flag, hb);
    ingest_xz<<<(NN * 3 + 255) / 256, 256, 0, stream>>>(xz, flag, xzf);
    ingest_misc<<<1, 256, 0, stream>>>(be1, be2, bn1, bn2, We1, flag, fb);
    swizzle_kernel<<<48, 256, 0, stream>>>(We1, We2, Wn1, Wn2, flag, We1s, We2s, Wn1s, Wn2s);
    hist_kernel<<<(EE + 255) / 256, 256, 0, stream>>>(erow, cntI);
    scan_kernel<<<1, 1024, 0, stream>>>(cntI, basep);
    scatter_kernel<<<(EE + 255) / 256, 256, 0, stream>>>(erow, ecol, basep, ctr, srow, scol);
    edge_kernel<<<768, 256, 0, stream>>>(hb, xzf, srow, scol, We1s, We2s, fb, agg);
    node_kernel<<<782, 256, 0, stream>>>(hb, h, agg, cntI, Wn1s, Wn2s, fb, flag, d_out);
}

// Round 6
// 605.461 us; speedup vs baseline: 1.2454x; 1.2454x over previous
//
#include <hip/hip_runtime.h>

#define NN 50000
#define EE 800000

typedef __bf16 bf16x8 __attribute__((ext_vector_type(8)));
typedef float  f32x4  __attribute__((ext_vector_type(4)));

__device__ __forceinline__ float bf2f(ushort u) {
    union { unsigned int i; float f; } v; v.i = ((unsigned int)u) << 16; return v.f;
}
__device__ __forceinline__ ushort f2bf(float f) {
    union { float f; unsigned int i; } v; v.f = f;
    unsigned int u = v.i;
    return (ushort)((u + 0x7FFFu + ((u >> 16) & 1u)) >> 16);
}
__device__ __forceinline__ float silu(float x) { return x / (1.0f + __expf(-x)); }

// ---------------------------------------------------------------------------
// Dtype detection (0 = bf16 inputs, 1 = f32 inputs).
// ---------------------------------------------------------------------------
__global__ void detect_kernel(const ushort* __restrict__ xzu, int* __restrict__ flag) {
    __shared__ int cnt;
    if (threadIdx.x == 0) cnt = 0;
    __syncthreads();
    float v = bf2f(xzu[2 * threadIdx.x]);
    bool sane = (v == v) && (fabsf(v) <= 4.0f);
    if (sane) atomicAdd(&cnt, 1);
    __syncthreads();
    if (threadIdx.x == 0) *flag = (cnt >= 192) ? 0 : 1;
}

// ---------------------------------------------------------------------------
// prep: blocks [0,25000) h->bf16; [25000,25587) xz->f32; [25587,28712) count
// ---------------------------------------------------------------------------
__global__ void prep_kernel(const void* __restrict__ hsrc, const void* __restrict__ xzsrc,
                            const int* __restrict__ erow, const int* __restrict__ flag,
                            ushort* __restrict__ hb, float* __restrict__ xzf,
                            int* __restrict__ cntI) {
    const bool isf = (*flag != 0);
    int b = blockIdx.x;
    if (b < 25000) {
        int i = b * 256 + threadIdx.x;
        hb[i] = isf ? f2bf(((const float*)hsrc)[i]) : ((const ushort*)hsrc)[i];
    } else if (b < 25587) {
        int i = (b - 25000) * 256 + threadIdx.x;
        if (i < NN * 3)
            xzf[i] = isf ? ((const float*)xzsrc)[i] : bf2f(((const ushort*)xzsrc)[i]);
    } else {
        int e = (b - 25587) * 256 + threadIdx.x;
        if (e < EE) atomicAdd(&cntI[erow[e]], 1);
    }
}

// ---------------------------------------------------------------------------
// swizzle (blocks 0..47) + misc f32 block (block 48):
// fb: [0:128)=be1 [128:256)=be2 [256:384)=bn1 [384:512)=bn2 [512:640)=We1[256][:]
// ---------------------------------------------------------------------------
__global__ void swizzle_misc_kernel(const void* We1, const void* We2,
                                    const void* Wn1, const void* Wn2,
                                    const void* be1, const void* be2,
                                    const void* bn1, const void* bn2,
                                    const int* __restrict__ flag,
                                    ushort* __restrict__ We1s, ushort* __restrict__ We2s,
                                    ushort* __restrict__ Wn1s, ushort* __restrict__ Wn2s,
                                    float* __restrict__ fb) {
    const bool isf = (*flag != 0);
    if (blockIdx.x == 48) {
        for (int j = threadIdx.x; j < 640; j += 256) {
            int which = j >> 7, k = j & 127;
            const void* src = (which == 0) ? be1 : (which == 1) ? be2 :
                              (which == 2) ? bn1 : (which == 3) ? bn2 : We1;
            size_t idx = (which == 4) ? ((size_t)256 * 128 + k) : (size_t)k;
            fb[j] = isf ? ((const float*)src)[idx] : bf2f(((const ushort*)src)[idx]);
        }
        return;
    }
    int c = blockIdx.x * 256 + threadIdx.x;
    const void* src; ushort* dst; int cl;
    if      (c <  4096) { src = We1; dst = We1s; cl = c;         }
    else if (c <  6144) { src = We2; dst = We2s; cl = c - 4096;  }
    else if (c < 10240) { src = Wn1; dst = Wn1s; cl = c - 6144;  }
    else                { src = Wn2; dst = Wn2s; cl = c - 10240; }
    int l = cl & 63, nt = (cl >> 6) & 7, kc = cl >> 9;
    int kbase = kc * 32 + (l >> 4) * 8;
    int n = nt * 16 + (l & 15);
    ushort tmp[8];
#pragma unroll
    for (int j = 0; j < 8; ++j) {
        size_t idx = (size_t)(kbase + j) * 128 + n;
        tmp[j] = isf ? f2bf(((const float*)src)[idx]) : ((const ushort*)src)[idx];
    }
#pragma unroll
    for (int j = 0; j < 8; ++j) dst[(size_t)cl * 8 + j] = tmp[j];
}

// ---------------------------------------------------------------------------
// Edge kernel, software-pipelined:
//   staging geometry: thread (w,lane) owns edge m=lane, chunks kb=w+4i (i<8)
//   -> needs only erow[e0+lane], ecol[e0+lane] + 8x16B gathers, all held in
//   registers one tile ahead. Prefetch issued AFTER barrier-A so the
//   compiler's vmcnt(0)-before-barrier drain lands after GEMM1+ep1 cover.
//   2 barriers/tile; sDist/sRowIdx double-buffered.
// ---------------------------------------------------------------------------
__global__ __launch_bounds__(256, 3) void edge_kernel(
    const ushort* __restrict__ hb, const float* __restrict__ xzf,
    const int* __restrict__ erow, const int* __restrict__ ecol,
    const ushort* __restrict__ We1s, const ushort* __restrict__ We2s,
    const float* __restrict__ fb, float* __restrict__ agg) {
    __shared__ __align__(16) ushort sA[16384];   // [quad][i(kc)][64 lanes][8] A-frags
    __shared__ __align__(16) ushort sM[8192];    // m1 frags
    __shared__ float sDist[2][64];
    __shared__ int   sRowIdx[2][64];

    const int tid = threadIdx.x;
    const int lane = tid & 63, w = tid >> 6;
    const int col = lane & 15, quad = lane >> 4;
    const int nt0 = w * 2;
    const int NT = EE / 64;
    const int stride = gridDim.x;

    // hoisted epilogue constants (per-thread, loop-invariant)
    const int nA = w * 32 + col, nB = nA + 16;
    const float be1A = fb[nA],       be1B = fb[nB];
    const float be2A = fb[128 + nA], be2B = fb[128 + nB];
    const float wlA  = fb[512 + nA], wlB  = fb[512 + nB];

    // preload all We2 B-fragments (loop-invariant): GEMM2 has zero VMEM
    bf16x8 B2[8];
#pragma unroll
    for (int kc = 0; kc < 4; ++kc) {
        B2[kc * 2]     = *(const bf16x8*)(We2s + ((kc * 8 + nt0)     * 64 + lane) * 8);
        B2[kc * 2 + 1] = *(const bf16x8*)(We2s + ((kc * 8 + nt0 + 1) * 64 + lane) * 8);
    }

    int t = blockIdx.x;
    if (t >= NT) return;

    // ---- prologue: gather tile t into regs; indices for t+stride ----
    int rA = erow[t * 64 + lane], cA = ecol[t * 64 + lane];
    uint4 hreg[8];
#pragma unroll
    for (int i = 0; i < 8; ++i) {
        int node = (i < 4) ? rA : cA;
        hreg[i] = *(const uint4*)(hb + (size_t)node * 128 + ((w + 4 * i) & 15) * 8);
    }
    float xz0 = 0, xz1 = 0, xz2 = 1, xz3 = 0, xz4 = 0, xz5 = 1;
    if (tid < 64) {
        xz0 = xzf[3 * rA]; xz1 = xzf[3 * rA + 1]; xz2 = xzf[3 * rA + 2];
        xz3 = xzf[3 * cA]; xz4 = xzf[3 * cA + 1]; xz5 = xzf[3 * cA + 2];
    }
    int rB = 0, cB = 0;
    if (t + stride < NT) {
        rB = erow[(t + stride) * 64 + lane];
        cB = ecol[(t + stride) * 64 + lane];
    }

    int par = 0;
    for (; t < NT; t += stride) {
        // ---- stage tile t from registers ----
#pragma unroll
        for (int i = 0; i < 8; ++i)
            *(uint4*)(sA + (((quad * 8 + i) * 64) + w * 16 + col) * 8) = hreg[i];
        if (tid < 64) {
            sRowIdx[par][tid] = rA;
            float dx = xz0 - xz3, dy = xz1 - xz4, dz = xz2 - xz5;
            float u = (dx * dx + dy * dy + dz * dz) / (2.0f * xz2 * xz5);
            u = fminf(fmaxf(u, 0.0f), 1.0e6f);
            sDist[par][tid] = __logf(1.0f + u + sqrtf(u * (u + 2.0f)));
        }
        __syncthreads();   // BARRIER-A: sA + meta ready (drains ep2 atomics of t-1)

        // ---- issue prefetch for t+stride (post-barrier so it stays in flight
        //      until BARRIER-B; GEMM1+ep1 cover the latency) ----
        const int tn = t + stride;
        if (tn < NT) {
            rA = rB; cA = cB;
#pragma unroll
            for (int i = 0; i < 8; ++i) {
                int node = (i < 4) ? rA : cA;
                hreg[i] = *(const uint4*)(hb + (size_t)node * 128 + ((w + 4 * i) & 15) * 8);
            }
            if (tn + stride < NT) {
                rB = erow[(tn + stride) * 64 + lane];
                cB = ecol[(tn + stride) * 64 + lane];
            }
            if (tid < 64) {
                xz0 = xzf[3 * rA]; xz1 = xzf[3 * rA + 1]; xz2 = xzf[3 * rA + 2];
                xz3 = xzf[3 * cA]; xz4 = xzf[3 * cA + 1]; xz5 = xzf[3 * cA + 2];
            }
        }

        // ---- GEMM1: [64,256] @ We1 (B-frags from L2) ----
        f32x4 acc[4][2] = {};
#pragma unroll
        for (int kc = 0; kc < 8; ++kc) {
            bf16x8 b0 = *(const bf16x8*)(We1s + ((kc * 8 + nt0)     * 64 + lane) * 8);
            bf16x8 b1 = *(const bf16x8*)(We1s + ((kc * 8 + nt0 + 1) * 64 + lane) * 8);
#pragma unroll
            for (int g = 0; g < 4; ++g) {
                bf16x8 a = *(const bf16x8*)(sA + ((g * 8 + kc) * 64 + lane) * 8);
                acc[g][0] = __builtin_amdgcn_mfma_f32_16x16x32_bf16(a, b0, acc[g][0], 0, 0, 0);
                acc[g][1] = __builtin_amdgcn_mfma_f32_16x16x32_bf16(a, b1, acc[g][1], 0, 0, 0);
            }
        }
        // ep1: + dist*We1[256] + be1, silu -> sM (A-frag order)
#pragma unroll
        for (int g = 0; g < 4; ++g) {
            int base0 = ((g * 4 + w) * 64 + (col >> 3) * 16) * 8 + (col & 7);
#pragma unroll
            for (int r = 0; r < 4; ++r) {
                int mrow = quad * 4 + r;
                float d = sDist[par][g * 16 + mrow];
                float x0 = acc[g][0][r] + d * wlA + be1A;
                float x1 = acc[g][1][r] + d * wlB + be1B;
                sM[base0 + mrow * 8]            = f2bf(silu(x0));
                sM[base0 + 2 * 16 * 8 + mrow * 8] = f2bf(silu(x1));
            }
        }
        __syncthreads();   // BARRIER-B: sM ready (drains the prefetch, now covered)

        // ---- GEMM2: m1 @ We2 (B from registers) ----
        f32x4 acc2[4][2] = {};
#pragma unroll
        for (int kc = 0; kc < 4; ++kc) {
#pragma unroll
            for (int g = 0; g < 4; ++g) {
                bf16x8 a = *(const bf16x8*)(sM + ((g * 4 + kc) * 64 + lane) * 8);
                acc2[g][0] = __builtin_amdgcn_mfma_f32_16x16x32_bf16(a, B2[kc * 2],     acc2[g][0], 0, 0, 0);
                acc2[g][1] = __builtin_amdgcn_mfma_f32_16x16x32_bf16(a, B2[kc * 2 + 1], acc2[g][1], 0, 0, 0);
            }
        }
        // ep2: silu(+be2) -> atomic scatter into agg[row]
#pragma unroll
        for (int g = 0; g < 4; ++g) {
#pragma unroll
            for (int r = 0; r < 4; ++r) {
                int m = g * 16 + quad * 4 + r;
                int row = sRowIdx[par][m];
                float x0 = silu(acc2[g][0][r] + be2A);
                float x1 = silu(acc2[g][1][r] + be2B);
                unsafeAtomicAdd(&agg[(size_t)row * 128 + nA], x0);
                unsafeAtomicAdd(&agg[(size_t)row * 128 + nB], x1);
            }
        }
        par ^= 1;
    }
}

// ---------------------------------------------------------------------------
// Node kernel: z = [h | agg/max(cnt,1)]; out = h + silu(z@Wn1+bn1)@Wn2+bn2
// ---------------------------------------------------------------------------
__global__ __launch_bounds__(256, 3) void node_kernel(
    const ushort* __restrict__ hb, const void* __restrict__ hraw,
    const float* __restrict__ agg, const int* __restrict__ cntI,
    const ushort* __restrict__ Wn1s, const ushort* __restrict__ Wn2s,
    const float* __restrict__ fb, const int* __restrict__ flag,
    void* __restrict__ outv) {
    __shared__ __align__(16) ushort sA[16384];
    __shared__ __align__(16) ushort sM[8192];
    const int tid = threadIdx.x;
    const int lane = tid & 63, w = tid >> 6;
    const int col = lane & 15, quad = lane >> 4;
    const int nt0 = w * 2;
    const int ntiles = (NN + 63) / 64;
    const bool isf = (*flag != 0);
    float* outf = (float*)outv;
    ushort* outu = (ushort*)outv;

    const int nA = w * 32 + col, nB = nA + 16;
    const float bn1A = fb[256 + nA], bn1B = fb[256 + nB];
    const float bn2A = fb[384 + nA], bn2B = fb[384 + nB];

    for (int tile = blockIdx.x; tile < ntiles; tile += gridDim.x) {
        __syncthreads();
        const int n0 = tile * 64;
#pragma unroll
        for (int i = 0; i < 8; ++i) {
            int kb = w + 4 * i;            // m = lane
            int node = n0 + lane;
            uint4 v;
            if (node < NN) {
                if (kb < 16) {
                    v = *(const uint4*)(hb + (size_t)node * 128 + kb * 8);
                } else {
                    const float* ap = agg + (size_t)node * 128 + (kb - 16) * 8;
                    float invc = 1.0f / fmaxf((float)cntI[node], 1.0f);
                    float4 f0 = *(const float4*)ap;
                    float4 f1 = *(const float4*)(ap + 4);
                    v.x = (unsigned int)f2bf(f0.x * invc) | ((unsigned int)f2bf(f0.y * invc) << 16);
                    v.y = (unsigned int)f2bf(f0.z * invc) | ((unsigned int)f2bf(f0.w * invc) << 16);
                    v.z = (unsigned int)f2bf(f1.x * invc) | ((unsigned int)f2bf(f1.y * invc) << 16);
                    v.w = (unsigned int)f2bf(f1.z * invc) | ((unsigned int)f2bf(f1.w * invc) << 16);
                }
            } else {
                v = make_uint4(0, 0, 0, 0);
            }
            *(uint4*)(sA + (((quad * 8 + i) * 64) + w * 16 + col) * 8) = v;
        }
        __syncthreads();

        f32x4 acc[4][2] = {};
#pragma unroll
        for (int kc = 0; kc < 8; ++kc) {
            bf16x8 b0 = *(const bf16x8*)(Wn1s + ((kc * 8 + nt0)     * 64 + lane) * 8);
            bf16x8 b1 = *(const bf16x8*)(Wn1s + ((kc * 8 + nt0 + 1) * 64 + lane) * 8);
#pragma unroll
            for (int g = 0; g < 4; ++g) {
                bf16x8 a = *(const bf16x8*)(sA + ((g * 8 + kc) * 64 + lane) * 8);
                acc[g][0] = __builtin_amdgcn_mfma_f32_16x16x32_bf16(a, b0, acc[g][0], 0, 0, 0);
                acc[g][1] = __builtin_amdgcn_mfma_f32_16x16x32_bf16(a, b1, acc[g][1], 0, 0, 0);
            }
        }
#pragma unroll
        for (int g = 0; g < 4; ++g) {
            int base0 = ((g * 4 + w) * 64 + (col >> 3) * 16) * 8 + (col & 7);
#pragma unroll
            for (int r = 0; r < 4; ++r) {
                int mrow = quad * 4 + r;
                sM[base0 + mrow * 8]              = f2bf(silu(acc[g][0][r] + bn1A));
                sM[base0 + 2 * 16 * 8 + mrow * 8] = f2bf(silu(acc[g][1][r] + bn1B));
            }
        }
        __syncthreads();

        f32x4 acc2[4][2] = {};
#pragma unroll
        for (int kc = 0; kc < 4; ++kc) {
            bf16x8 b0 = *(const bf16x8*)(Wn2s + ((kc * 8 + nt0)     * 64 + lane) * 8);
            bf16x8 b1 = *(const bf16x8*)(Wn2s + ((kc * 8 + nt0 + 1) * 64 + lane) * 8);
#pragma unroll
            for (int g = 0; g < 4; ++g) {
                bf16x8 a = *(const bf16x8*)(sM + ((g * 4 + kc) * 64 + lane) * 8);
                acc2[g][0] = __builtin_amdgcn_mfma_f32_16x16x32_bf16(a, b0, acc2[g][0], 0, 0, 0);
                acc2[g][1] = __builtin_amdgcn_mfma_f32_16x16x32_bf16(a, b1, acc2[g][1], 0, 0, 0);
            }
        }
#pragma unroll
        for (int g = 0; g < 4; ++g) {
#pragma unroll
            for (int r = 0; r < 4; ++r) {
                int ml2 = g * 16 + quad * 4 + r;
                int node = n0 + ml2;
                if (node < NN) {
                    size_t oi = (size_t)node * 128;
                    float h0 = isf ? ((const float*)hraw)[oi + nA] : bf2f(((const ushort*)hraw)[oi + nA]);
                    float h1 = isf ? ((const float*)hraw)[oi + nB] : bf2f(((const ushort*)hraw)[oi + nB]);
                    float x0 = acc2[g][0][r] + bn2A + h0;
                    float x1 = acc2[g][1][r] + bn2B + h1;
                    if (isf) { outf[oi + nA] = x0; outf[oi + nB] = x1; }
                    else     { outu[oi + nA] = f2bf(x0); outu[oi + nB] = f2bf(x1); }
                }
            }
        }
    }
}

extern "C" void kernel_launch(void* const* d_in, const int* in_sizes, int n_in,
                              void* d_out, int out_size, void* d_ws, size_t ws_size,
                              hipStream_t stream) {
    const void* xz  = d_in[0];
    const void* h   = d_in[1];
    const void* We1 = d_in[2];
    const void* be1 = d_in[3];
    const void* We2 = d_in[4];
    const void* be2 = d_in[5];
    const void* Wn1 = d_in[6];
    const void* bn1 = d_in[7];
    const void* Wn2 = d_in[8];
    const void* bn2 = d_in[9];
    const int*  ei  = (const int*)d_in[10];
    const int* erow = ei;
    const int* ecol = ei + EE;

    char* base = (char*)d_ws;
    size_t cur = 0;
    auto alloc = [&](size_t bytes) { size_t o = cur; cur = (cur + bytes + 255) & ~(size_t)255; return o; };
    int*    flag = (int*)   (base + alloc(16));
    float*  agg  = (float*) (base + alloc((size_t)NN * 128 * 4));
    int*    cntI = (int*)   (base + alloc((size_t)NN * 4));
    ushort* hb   = (ushort*)(base + alloc((size_t)NN * 128 * 2));
    float*  xzf  = (float*) (base + alloc((size_t)NN * 3 * 4));
    ushort* We1s = (ushort*)(base + alloc(32768 * 2));
    ushort* We2s = (ushort*)(base + alloc(16384 * 2));
    ushort* Wn1s = (ushort*)(base + alloc(32768 * 2));
    ushort* Wn2s = (ushort*)(base + alloc(16384 * 2));
    float*  fb   = (float*) (base + alloc(640 * 4));

    // one memset covers agg + cntI (adjacent allocations)
    size_t zbytes = (size_t)((char*)cntI - (char*)agg) + (size_t)NN * 4;
    (void)hipMemsetAsync(agg, 0, zbytes, stream);

    detect_kernel<<<1, 256, 0, stream>>>((const ushort*)xz, flag);
    prep_kernel<<<28712, 256, 0, stream>>>(h, xz, erow, flag, hb, xzf, cntI);
    swizzle_misc_kernel<<<49, 256, 0, stream>>>(We1, We2, Wn1, Wn2, be1, be2, bn1, bn2,
                                                flag, We1s, We2s, Wn1s, Wn2s, fb);
    edge_kernel<<<768, 256, 0, stream>>>(hb, xzf, erow, ecol, We1s, We2s, fb, agg);
    node_kernel<<<782, 256, 0, stream>>>(hb, h, agg, cntI, Wn1s, Wn2s, fb, flag, d_out);
}

// Round 7
// 603.648 us; speedup vs baseline: 1.2491x; 1.0030x over previous
//
#include <hip/hip_runtime.h>

#define NN 50000
#define EE 800000

typedef __bf16 bf16x8 __attribute__((ext_vector_type(8)));
typedef float  f32x4  __attribute__((ext_vector_type(4)));

__device__ __forceinline__ float bf2f(ushort u) {
    union { unsigned int i; float f; } v; v.i = ((unsigned int)u) << 16; return v.f;
}
__device__ __forceinline__ ushort f2bf(float f) {        // RNE (weights/one-time)
    union { float f; unsigned int i; } v; v.f = f;
    unsigned int u = v.i;
    return (ushort)((u + 0x7FFFu + ((u >> 16) & 1u)) >> 16);
}
__device__ __forceinline__ ushort f2bf_fast(float f) {   // cheap round (epilogues)
    union { float f; unsigned int i; } v; v.f = f;
    return (ushort)((v.i + 0x8000u) >> 16);
}
__device__ __forceinline__ float silu(float x) { return x / (1.0f + __expf(-x)); }

// ---------------------------------------------------------------------------
// Dtype detection (0 = bf16 inputs, 1 = f32 inputs).
// ---------------------------------------------------------------------------
__global__ void detect_kernel(const ushort* __restrict__ xzu, int* __restrict__ flag) {
    __shared__ int cnt;
    if (threadIdx.x == 0) cnt = 0;
    __syncthreads();
    float v = bf2f(xzu[2 * threadIdx.x]);
    bool sane = (v == v) && (fabsf(v) <= 4.0f);
    if (sane) atomicAdd(&cnt, 1);
    __syncthreads();
    if (threadIdx.x == 0) *flag = (cnt >= 192) ? 0 : 1;
}

// ---------------------------------------------------------------------------
// prep: blocks [0,25000) h->bf16; [25000,25587) xz->f32; [25587,28712) count
// ---------------------------------------------------------------------------
__global__ void prep_kernel(const void* __restrict__ hsrc, const void* __restrict__ xzsrc,
                            const int* __restrict__ erow, const int* __restrict__ flag,
                            ushort* __restrict__ hb, float* __restrict__ xzf,
                            int* __restrict__ cntI) {
    const bool isf = (*flag != 0);
    int b = blockIdx.x;
    if (b < 25000) {
        int i = b * 256 + threadIdx.x;
        hb[i] = isf ? f2bf(((const float*)hsrc)[i]) : ((const ushort*)hsrc)[i];
    } else if (b < 25587) {
        int i = (b - 25000) * 256 + threadIdx.x;
        if (i < NN * 3)
            xzf[i] = isf ? ((const float*)xzsrc)[i] : bf2f(((const ushort*)xzsrc)[i]);
    } else {
        int e = (b - 25587) * 256 + threadIdx.x;
        if (e < EE) atomicAdd(&cntI[erow[e]], 1);
    }
}

// ---------------------------------------------------------------------------
// swizzle (blocks 0..47) + misc f32 block (block 48):
// fb: [0:128)=be1 [128:256)=be2 [256:384)=bn1 [384:512)=bn2 [512:640)=We1[256][:]
// ---------------------------------------------------------------------------
__global__ void swizzle_misc_kernel(const void* We1, const void* We2,
                                    const void* Wn1, const void* Wn2,
                                    const void* be1, const void* be2,
                                    const void* bn1, const void* bn2,
                                    const int* __restrict__ flag,
                                    ushort* __restrict__ We1s, ushort* __restrict__ We2s,
                                    ushort* __restrict__ Wn1s, ushort* __restrict__ Wn2s,
                                    float* __restrict__ fb) {
    const bool isf = (*flag != 0);
    if (blockIdx.x == 48) {
        for (int j = threadIdx.x; j < 640; j += 256) {
            int which = j >> 7, k = j & 127;
            const void* src = (which == 0) ? be1 : (which == 1) ? be2 :
                              (which == 2) ? bn1 : (which == 3) ? bn2 : We1;
            size_t idx = (which == 4) ? ((size_t)256 * 128 + k) : (size_t)k;
            fb[j] = isf ? ((const float*)src)[idx] : bf2f(((const ushort*)src)[idx]);
        }
        return;
    }
    int c = blockIdx.x * 256 + threadIdx.x;
    const void* src; ushort* dst; int cl;
    if      (c <  4096) { src = We1; dst = We1s; cl = c;         }
    else if (c <  6144) { src = We2; dst = We2s; cl = c - 4096;  }
    else if (c < 10240) { src = Wn1; dst = Wn1s; cl = c - 6144;  }
    else                { src = Wn2; dst = Wn2s; cl = c - 10240; }
    int l = cl & 63, nt = (cl >> 6) & 7, kc = cl >> 9;
    int kbase = kc * 32 + (l >> 4) * 8;
    int n = nt * 16 + (l & 15);
    ushort tmp[8];
#pragma unroll
    for (int j = 0; j < 8; ++j) {
        size_t idx = (size_t)(kbase + j) * 128 + n;
        tmp[j] = isf ? f2bf(((const float*)src)[idx]) : ((const ushort*)src)[idx];
    }
#pragma unroll
    for (int j = 0; j < 8; ++j) dst[(size_t)cl * 8 + j] = tmp[j];
}

// ---------------------------------------------------------------------------
// Edge kernel, 32-edge tiles, row-major LDS A with XOR-slot swizzle.
//   sRow[r][128 bf16], r<32: h[erow[e0+r]], r>=32: h[ecol[e0+r-32]].
//   16B chunk slot s of row r holds global chunk s^(r&7)  (bank-conflict-free
//   for both coalesced staging writes and MFMA A-frag ds_read_b128).
//   LDS = 16KB(sRow) + 8KB(sM) + meta ~= 24.5KB; launch_bounds(256,4)
//   -> 4 blocks/CU, 16 waves (vs 34% occ before). No cross-barrier reg cargo.
// ---------------------------------------------------------------------------
__global__ __launch_bounds__(256, 4) void edge_kernel(
    const ushort* __restrict__ hb, const float* __restrict__ xzf,
    const int* __restrict__ erow, const int* __restrict__ ecol,
    const ushort* __restrict__ We1s, const ushort* __restrict__ We2s,
    const float* __restrict__ fb, float* __restrict__ agg) {
    __shared__ __align__(16) ushort sRow[8192];   // 16KB: 64 rows x 256B
    __shared__ __align__(16) ushort sM[4096];     // 8KB: m1[32][128] (same swizzle)
    __shared__ float sDist[2][32];
    __shared__ int   sRowIdx[2][32];

    const int tid = threadIdx.x;
    const int lane = tid & 63, w = tid >> 6;
    const int col = lane & 15, quad = lane >> 4;
    const int nt0 = w * 2;
    const int NT = EE / 32;          // 25000 tiles
    const int stride = gridDim.x;

    const int nA = w * 32 + col, nB = nA + 16;
    const float be1A = fb[nA],       be1B = fb[nB];
    const float be2A = fb[128 + nA], be2B = fb[128 + nB];
    const float wlA  = fb[512 + nA], wlB  = fb[512 + nB];

    // We2 B-fragments in registers (loop-invariant, GEMM2 has zero VMEM)
    bf16x8 B2[8];
#pragma unroll
    for (int kc = 0; kc < 4; ++kc) {
        B2[kc * 2]     = *(const bf16x8*)(We2s + ((kc * 8 + nt0)     * 64 + lane) * 8);
        B2[kc * 2 + 1] = *(const bf16x8*)(We2s + ((kc * 8 + nt0 + 1) * 64 + lane) * 8);
    }

    int par = 0;
    for (int tile = blockIdx.x; tile < NT; tile += stride) {
        const int e0 = tile * 32;
        // ---- staging: 16 row-groups of 4 rows; wave w does groups i*4+w ----
#pragma unroll
        for (int i = 0; i < 4; ++i) {
            int r = (i * 4 + w) * 4 + (lane >> 4);        // 0..63
            int eidx = e0 + (r & 31);
            int node = (r < 32) ? erow[eidx] : ecol[eidx];
            uint4 v = *(const uint4*)(hb + (size_t)node * 128 + col * 8);
            *(uint4*)(sRow + (size_t)r * 128 + ((col ^ (r & 7)) * 8)) = v;
        }
        if (tid < 32) {
            int e = e0 + tid;
            int r = erow[e], c = ecol[e];
            sRowIdx[par][tid] = r;
            float x1 = xzf[3 * r], y1 = xzf[3 * r + 1], z1 = xzf[3 * r + 2];
            float x2 = xzf[3 * c], y2 = xzf[3 * c + 1], z2 = xzf[3 * c + 2];
            float dx = x1 - x2, dy = y1 - y2, dz = z1 - z2;
            float u = (dx * dx + dy * dy + dz * dz) / (2.0f * z1 * z2);
            u = fminf(fmaxf(u, 0.0f), 1.0e6f);
            sDist[par][tid] = __logf(1.0f + u + sqrtf(u * (u + 2.0f)));
        }
        __syncthreads();   // BARRIER-A: sRow/meta ready; previous GEMM2 done

        // ---- GEMM1: [32,256] @ We1 -> acc[2][2] ----
        f32x4 acc[2][2] = {};
#pragma unroll
        for (int kc = 0; kc < 8; ++kc) {
            bf16x8 b0 = *(const bf16x8*)(We1s + ((kc * 8 + nt0)     * 64 + lane) * 8);
            bf16x8 b1 = *(const bf16x8*)(We1s + ((kc * 8 + nt0 + 1) * 64 + lane) * 8);
#pragma unroll
            for (int g = 0; g < 2; ++g) {
                int r = ((kc < 4) ? 0 : 32) + g * 16 + col;   // row in sRow
                int cR = (kc & 3) * 4 + quad;                 // chunk within row
                bf16x8 a = *(const bf16x8*)(sRow + r * 128 + ((cR ^ (r & 7)) * 8));
                acc[g][0] = __builtin_amdgcn_mfma_f32_16x16x32_bf16(a, b0, acc[g][0], 0, 0, 0);
                acc[g][1] = __builtin_amdgcn_mfma_f32_16x16x32_bf16(a, b1, acc[g][1], 0, 0, 0);
            }
        }
        // ep1: + dist*We1[256] + be1, silu -> sM (swizzled row-major)
#pragma unroll
        for (int g = 0; g < 2; ++g) {
#pragma unroll
            for (int r4 = 0; r4 < 4; ++r4) {
                int m = g * 16 + quad * 4 + r4;
                float d = sDist[par][m];
                float x0 = acc[g][0][r4] + d * wlA + be1A;
                float x1 = acc[g][1][r4] + d * wlB + be1B;
                sM[m * 128 + ((nA >> 3) ^ (m & 7)) * 8 + (nA & 7)] = f2bf_fast(silu(x0));
                sM[m * 128 + ((nB >> 3) ^ (m & 7)) * 8 + (nB & 7)] = f2bf_fast(silu(x1));
            }
        }
        __syncthreads();   // BARRIER-B: sM ready; all GEMM1 sRow reads done

        // ---- GEMM2: m1[32,128] @ We2 (B in regs) ----
        f32x4 acc2[2][2] = {};
#pragma unroll
        for (int kc = 0; kc < 4; ++kc) {
#pragma unroll
            for (int g = 0; g < 2; ++g) {
                int r2 = g * 16 + col;
                int c2 = kc * 4 + quad;
                bf16x8 a = *(const bf16x8*)(sM + r2 * 128 + ((c2 ^ (r2 & 7)) * 8));
                acc2[g][0] = __builtin_amdgcn_mfma_f32_16x16x32_bf16(a, B2[kc * 2],     acc2[g][0], 0, 0, 0);
                acc2[g][1] = __builtin_amdgcn_mfma_f32_16x16x32_bf16(a, B2[kc * 2 + 1], acc2[g][1], 0, 0, 0);
            }
        }
        // ep2: silu(+be2) -> atomics into agg[row]
#pragma unroll
        for (int g = 0; g < 2; ++g) {
#pragma unroll
            for (int r4 = 0; r4 < 4; ++r4) {
                int m = g * 16 + quad * 4 + r4;
                int row = sRowIdx[par][m];
                unsafeAtomicAdd(&agg[(size_t)row * 128 + nA], silu(acc2[g][0][r4] + be2A));
                unsafeAtomicAdd(&agg[(size_t)row * 128 + nB], silu(acc2[g][1][r4] + be2B));
            }
        }
        par ^= 1;
    }
}

// ---------------------------------------------------------------------------
// Node kernel: z = [h | agg/max(cnt,1)]; out = h + silu(z@Wn1+bn1)@Wn2+bn2
// ---------------------------------------------------------------------------
__global__ __launch_bounds__(256, 3) void node_kernel(
    const ushort* __restrict__ hb, const void* __restrict__ hraw,
    const float* __restrict__ agg, const int* __restrict__ cntI,
    const ushort* __restrict__ Wn1s, const ushort* __restrict__ Wn2s,
    const float* __restrict__ fb, const int* __restrict__ flag,
    void* __restrict__ outv) {
    __shared__ __align__(16) ushort sA[16384];
    __shared__ __align__(16) ushort sM[8192];
    const int tid = threadIdx.x;
    const int lane = tid & 63, w = tid >> 6;
    const int col = lane & 15, quad = lane >> 4;
    const int nt0 = w * 2;
    const int ntiles = (NN + 63) / 64;
    const bool isf = (*flag != 0);
    float* outf = (float*)outv;
    ushort* outu = (ushort*)outv;

    const int nA = w * 32 + col, nB = nA + 16;
    const float bn1A = fb[256 + nA], bn1B = fb[256 + nB];
    const float bn2A = fb[384 + nA], bn2B = fb[384 + nB];

    for (int tile = blockIdx.x; tile < ntiles; tile += gridDim.x) {
        __syncthreads();
        const int n0 = tile * 64;
#pragma unroll
        for (int i = 0; i < 8; ++i) {
            int kb = w + 4 * i;            // m = lane
            int node = n0 + lane;
            uint4 v;
            if (node < NN) {
                if (kb < 16) {
                    v = *(const uint4*)(hb + (size_t)node * 128 + kb * 8);
                } else {
                    const float* ap = agg + (size_t)node * 128 + (kb - 16) * 8;
                    float invc = 1.0f / fmaxf((float)cntI[node], 1.0f);
                    float4 f0 = *(const float4*)ap;
                    float4 f1 = *(const float4*)(ap + 4);
                    v.x = (unsigned int)f2bf_fast(f0.x * invc) | ((unsigned int)f2bf_fast(f0.y * invc) << 16);
                    v.y = (unsigned int)f2bf_fast(f0.z * invc) | ((unsigned int)f2bf_fast(f0.w * invc) << 16);
                    v.z = (unsigned int)f2bf_fast(f1.x * invc) | ((unsigned int)f2bf_fast(f1.y * invc) << 16);
                    v.w = (unsigned int)f2bf_fast(f1.z * invc) | ((unsigned int)f2bf_fast(f1.w * invc) << 16);
                }
            } else {
                v = make_uint4(0, 0, 0, 0);
            }
            *(uint4*)(sA + (((quad * 8 + i) * 64) + w * 16 + col) * 8) = v;
        }
        __syncthreads();

        f32x4 acc[4][2] = {};
#pragma unroll
        for (int kc = 0; kc < 8; ++kc) {
            bf16x8 b0 = *(const bf16x8*)(Wn1s + ((kc * 8 + nt0)     * 64 + lane) * 8);
            bf16x8 b1 = *(const bf16x8*)(Wn1s + ((kc * 8 + nt0 + 1) * 64 + lane) * 8);
#pragma unroll
            for (int g = 0; g < 4; ++g) {
                bf16x8 a = *(const bf16x8*)(sA + ((g * 8 + kc) * 64 + lane) * 8);
                acc[g][0] = __builtin_amdgcn_mfma_f32_16x16x32_bf16(a, b0, acc[g][0], 0, 0, 0);
                acc[g][1] = __builtin_amdgcn_mfma_f32_16x16x32_bf16(a, b1, acc[g][1], 0, 0, 0);
            }
        }
#pragma unroll
        for (int g = 0; g < 4; ++g) {
            int base0 = ((g * 4 + w) * 64 + (col >> 3) * 16) * 8 + (col & 7);
#pragma unroll
            for (int r = 0; r < 4; ++r) {
                int mrow = quad * 4 + r;
                sM[base0 + mrow * 8]              = f2bf_fast(silu(acc[g][0][r] + bn1A));
                sM[base0 + 2 * 16 * 8 + mrow * 8] = f2bf_fast(silu(acc[g][1][r] + bn1B));
            }
        }
        __syncthreads();

        f32x4 acc2[4][2] = {};
#pragma unroll
        for (int kc = 0; kc < 4; ++kc) {
            bf16x8 b0 = *(const bf16x8*)(Wn2s + ((kc * 8 + nt0)     * 64 + lane) * 8);
            bf16x8 b1 = *(const bf16x8*)(Wn2s + ((kc * 8 + nt0 + 1) * 64 + lane) * 8);
#pragma unroll
            for (int g = 0; g < 4; ++g) {
                bf16x8 a = *(const bf16x8*)(sM + ((g * 4 + kc) * 64 + lane) * 8);
                acc2[g][0] = __builtin_amdgcn_mfma_f32_16x16x32_bf16(a, b0, acc2[g][0], 0, 0, 0);
                acc2[g][1] = __builtin_amdgcn_mfma_f32_16x16x32_bf16(a, b1, acc2[g][1], 0, 0, 0);
            }
        }
#pragma unroll
        for (int g = 0; g < 4; ++g) {
#pragma unroll
            for (int r = 0; r < 4; ++r) {
                int ml2 = g * 16 + quad * 4 + r;
                int node = n0 + ml2;
                if (node < NN) {
                    size_t oi = (size_t)node * 128;
                    float h0 = isf ? ((const float*)hraw)[oi + nA] : bf2f(((const ushort*)hraw)[oi + nA]);
                    float h1 = isf ? ((const float*)hraw)[oi + nB] : bf2f(((const ushort*)hraw)[oi + nB]);
                    float x0 = acc2[g][0][r] + bn2A + h0;
                    float x1 = acc2[g][1][r] + bn2B + h1;
                    if (isf) { outf[oi + nA] = x0; outf[oi + nB] = x1; }
                    else     { outu[oi + nA] = f2bf_fast(x0); outu[oi + nB] = f2bf_fast(x1); }
                }
            }
        }
    }
}

extern "C" void kernel_launch(void* const* d_in, const int* in_sizes, int n_in,
                              void* d_out, int out_size, void* d_ws, size_t ws_size,
                              hipStream_t stream) {
    const void* xz  = d_in[0];
    const void* h   = d_in[1];
    const void* We1 = d_in[2];
    const void* be1 = d_in[3];
    const void* We2 = d_in[4];
    const void* be2 = d_in[5];
    const void* Wn1 = d_in[6];
    const void* bn1 = d_in[7];
    const void* Wn2 = d_in[8];
    const void* bn2 = d_in[9];
    const int*  ei  = (const int*)d_in[10];
    const int* erow = ei;
    const int* ecol = ei + EE;

    char* base = (char*)d_ws;
    size_t cur = 0;
    auto alloc = [&](size_t bytes) { size_t o = cur; cur = (cur + bytes + 255) & ~(size_t)255; return o; };
    int*    flag = (int*)   (base + alloc(16));
    float*  agg  = (float*) (base + alloc((size_t)NN * 128 * 4));
    int*    cntI = (int*)   (base + alloc((size_t)NN * 4));
    ushort* hb   = (ushort*)(base + alloc((size_t)NN * 128 * 2));
    float*  xzf  = (float*) (base + alloc((size_t)NN * 3 * 4));
    ushort* We1s = (ushort*)(base + alloc(32768 * 2));
    ushort* We2s = (ushort*)(base + alloc(16384 * 2));
    ushort* Wn1s = (ushort*)(base + alloc(32768 * 2));
    ushort* Wn2s = (ushort*)(base + alloc(16384 * 2));
    float*  fb   = (float*) (base + alloc(640 * 4));

    size_t zbytes = (size_t)((char*)cntI - (char*)agg) + (size_t)NN * 4;
    (void)hipMemsetAsync(agg, 0, zbytes, stream);

    detect_kernel<<<1, 256, 0, stream>>>((const ushort*)xz, flag);
    prep_kernel<<<28712, 256, 0, stream>>>(h, xz, erow, flag, hb, xzf, cntI);
    swizzle_misc_kernel<<<49, 256, 0, stream>>>(We1, We2, Wn1, Wn2, be1, be2, bn1, bn2,
                                                flag, We1s, We2s, Wn1s, Wn2s, fb);
    edge_kernel<<<1024, 256, 0, stream>>>(hb, xzf, erow, ecol, We1s, We2s, fb, agg);
    node_kernel<<<782, 256, 0, stream>>>(hb, h, agg, cntI, Wn1s, Wn2s, fb, flag, d_out);
}